// Round 1
// baseline (2222.827 us; speedup 1.0000x reference)
//
#include <hip/hip_runtime.h>
#include <stdint.h>

// ---------------------------------------------------------------------------
// GNN layer: e = ea@We+be; msg=relu(x[src]+e); aggr=seg_sum(msg,dst);
// h = relu((x+aggr)@W1+b1)@W2+b2; out = batchnorm(h)
// All GEMMs in bf16 MFMA (16x16x32), fp32 accumulate. Threshold 0.134 allows it.
// ---------------------------------------------------------------------------

typedef __attribute__((ext_vector_type(8))) short short8;   // 8 bf16 = 4 VGPRs
typedef __attribute__((ext_vector_type(4))) float floatx4;  // MFMA C/D

__device__ __forceinline__ unsigned short f2bf(float f) {
  unsigned int u = __float_as_uint(f);
  u += 0x7FFFu + ((u >> 16) & 1u);   // round-to-nearest-even
  return (unsigned short)(u >> 16);
}

__device__ __forceinline__ void async_copy16(const void* g, void* l) {
  __builtin_amdgcn_global_load_lds(
      (const __attribute__((address_space(1))) void*)g,
      (__attribute__((address_space(3))) void*)l, 16, 0, 0);
}

// 128x128 tile, BK=32, 256 threads (4 waves, each 64x64 = 4x4 MFMA tiles).
// A: [M,512] bf16 row-major. B: [N,512] bf16 row-major (i.e. W^T). K=512.
// LDS layout: row-major [128][32] bf16, 16B chunks XOR-swizzled by (row>>1)&3
// (swizzle applied on the GLOBAL source address so global_load_lds's
// wave-uniform-base+lane*16 destination rule is preserved).
__device__ __forceinline__ void gemm_mainloop(
    const unsigned short* __restrict__ A, int arow0, int amax,
    const unsigned short* __restrict__ B, int brow0,
    unsigned short* As, unsigned short* Bs, floatx4 acc[4][4]) {
  const int t    = threadIdx.x;
  const int w    = t >> 6;
  const int l    = t & 63;
  const int quad = l >> 4;
  const int t16  = l & 15;
  const int wm   = (w >> 1) * 64;
  const int wn   = (w & 1) * 64;
  const int sm   = t >> 2;   // staging row (first 64-row half)
  const int ssl  = t & 3;    // staging 16B slot within row

  for (int kt = 0; kt < 512; kt += 32) {
    __syncthreads();   // prev iter's ds_reads done before overwrite
#pragma unroll
    for (int p = 0; p < 2; ++p) {
      const int m = sm + p * 64;
      const int c = ssl ^ ((m >> 1) & 3);        // global chunk for this slot
      int ra = arow0 + m; ra = ra > amax ? amax : ra;
      const char* ga = (const char*)A + ((size_t)ra * 512 + kt) * 2 + c * 16;
      async_copy16(ga, (char*)As + w * 1024 + p * 4096);
      const int rb = brow0 + m;                  // always < 512, no clamp
      const char* gb = (const char*)B + ((size_t)rb * 512 + kt) * 2 + c * 16;
      async_copy16(gb, (char*)Bs + w * 1024 + p * 4096);
    }
    __syncthreads();   // compiler emits s_waitcnt vmcnt(0) before s_barrier

    short8 af[4], bf[4];
#pragma unroll
    for (int i = 0; i < 4; ++i) {
      const int row = wm + i * 16 + t16;
      const int s   = quad ^ ((row >> 1) & 3);
      af[i] = *(const short8*)((const char*)As + row * 64 + s * 16);
    }
#pragma unroll
    for (int j = 0; j < 4; ++j) {
      const int row = wn + j * 16 + t16;
      const int s   = quad ^ ((row >> 1) & 3);
      bf[j] = *(const short8*)((const char*)Bs + row * 64 + s * 16);
    }
#pragma unroll
    for (int i = 0; i < 4; ++i)
#pragma unroll
      for (int j = 0; j < 4; ++j)
        acc[i][j] = __builtin_amdgcn_mfma_f32_16x16x32_bf16(af[i], bf[j],
                                                            acc[i][j], 0, 0, 0);
  }
}

// ---- edge GEMM fused with gather+relu+scatter-add ---------------------------
__global__ __launch_bounds__(256) void edge_gemm(
    const unsigned short* __restrict__ A, const unsigned short* __restrict__ BT,
    const float* __restrict__ be_, const float* __restrict__ x,
    const int* __restrict__ src, const int* __restrict__ dst,
    float* __restrict__ aggr, int E) {
  __shared__ unsigned short As[4096];
  __shared__ unsigned short Bs[4096];
  floatx4 acc[4][4];
#pragma unroll
  for (int i = 0; i < 4; ++i)
#pragma unroll
    for (int j = 0; j < 4; ++j) { floatx4 z = {0.f, 0.f, 0.f, 0.f}; acc[i][j] = z; }

  const int mrow0 = (blockIdx.x >> 2) * 128;
  const int ncol0 = (blockIdx.x & 3) * 128;
  gemm_mainloop(A, mrow0, E - 1, BT, ncol0, As, Bs, acc);

  const int t = threadIdx.x, w = t >> 6, l = t & 63, quad = l >> 4, t16 = l & 15;
  const int wm = (w >> 1) * 64, wn = (w & 1) * 64;
  float be[4];
#pragma unroll
  for (int j = 0; j < 4; ++j) be[j] = be_[ncol0 + wn + j * 16 + t16];
#pragma unroll
  for (int i = 0; i < 4; ++i) {
#pragma unroll
    for (int r = 0; r < 4; ++r) {
      const int e = mrow0 + wm + i * 16 + quad * 4 + r;   // C/D: row=quad*4+reg
      if (e < E) {
        const int sn = src[e], dn = dst[e];
        const float* xr = x + (size_t)sn * 512 + ncol0 + wn + t16;
        float* ar = aggr + (size_t)dn * 512 + ncol0 + wn + t16;
#pragma unroll
        for (int j = 0; j < 4; ++j) {
          float v = acc[i][j][r] + be[j] + xr[j * 16];
          v = v > 0.f ? v : 0.f;
          atomicAdd(ar + j * 16, v);
        }
      }
    }
  }
}

// ---- node GEMM, relu epilogue, bf16 out ------------------------------------
__global__ __launch_bounds__(256) void node_gemm_relu(
    const unsigned short* __restrict__ A, const unsigned short* __restrict__ BT,
    const float* __restrict__ bias, unsigned short* __restrict__ out, int M) {
  __shared__ unsigned short As[4096];
  __shared__ unsigned short Bs[4096];
  floatx4 acc[4][4];
#pragma unroll
  for (int i = 0; i < 4; ++i)
#pragma unroll
    for (int j = 0; j < 4; ++j) { floatx4 z = {0.f, 0.f, 0.f, 0.f}; acc[i][j] = z; }
  const int mrow0 = (blockIdx.x >> 2) * 128;
  const int ncol0 = (blockIdx.x & 3) * 128;
  gemm_mainloop(A, mrow0, M - 1, BT, ncol0, As, Bs, acc);

  const int t = threadIdx.x, w = t >> 6, l = t & 63, quad = l >> 4, t16 = l & 15;
  const int wm = (w >> 1) * 64, wn = (w & 1) * 64;
  float bb[4];
#pragma unroll
  for (int j = 0; j < 4; ++j) bb[j] = bias[ncol0 + wn + j * 16 + t16];
#pragma unroll
  for (int i = 0; i < 4; ++i) {
#pragma unroll
    for (int r = 0; r < 4; ++r) {
      const int gm = mrow0 + wm + i * 16 + quad * 4 + r;
      if (gm < M) {
        unsigned short* orow = out + (size_t)gm * 512 + ncol0 + wn + t16;
#pragma unroll
        for (int j = 0; j < 4; ++j) {
          float v = acc[i][j][r] + bb[j];
          v = v > 0.f ? v : 0.f;
          orow[j * 16] = f2bf(v);
        }
      }
    }
  }
}

// ---- node GEMM, plain epilogue, fp32 out -----------------------------------
__global__ __launch_bounds__(256) void node_gemm_f32(
    const unsigned short* __restrict__ A, const unsigned short* __restrict__ BT,
    const float* __restrict__ bias, float* __restrict__ out, int M) {
  __shared__ unsigned short As[4096];
  __shared__ unsigned short Bs[4096];
  floatx4 acc[4][4];
#pragma unroll
  for (int i = 0; i < 4; ++i)
#pragma unroll
    for (int j = 0; j < 4; ++j) { floatx4 z = {0.f, 0.f, 0.f, 0.f}; acc[i][j] = z; }
  const int mrow0 = (blockIdx.x >> 2) * 128;
  const int ncol0 = (blockIdx.x & 3) * 128;
  gemm_mainloop(A, mrow0, M - 1, BT, ncol0, As, Bs, acc);

  const int t = threadIdx.x, w = t >> 6, l = t & 63, quad = l >> 4, t16 = l & 15;
  const int wm = (w >> 1) * 64, wn = (w & 1) * 64;
  float bb[4];
#pragma unroll
  for (int j = 0; j < 4; ++j) bb[j] = bias[ncol0 + wn + j * 16 + t16];
#pragma unroll
  for (int i = 0; i < 4; ++i) {
#pragma unroll
    for (int r = 0; r < 4; ++r) {
      const int gm = mrow0 + wm + i * 16 + quad * 4 + r;
      if (gm < M) {
        float* orow = out + (size_t)gm * 512 + ncol0 + wn + t16;
#pragma unroll
        for (int j = 0; j < 4; ++j) orow[j * 16] = acc[i][j][r] + bb[j];
      }
    }
  }
}

// ---- helpers ---------------------------------------------------------------
__global__ __launch_bounds__(256) void cvt_f32_bf16(
    const float* __restrict__ in, unsigned short* __restrict__ out, int n4) {
  const int i = blockIdx.x * 256 + threadIdx.x;
  if (i < n4) {
    float4 v = ((const float4*)in)[i];
    ushort4 o;
    o.x = f2bf(v.x); o.y = f2bf(v.y); o.z = f2bf(v.z); o.w = f2bf(v.w);
    ((ushort4*)out)[i] = o;
  }
}

// W [512][512] f32 -> W^T [512][512] bf16
__global__ __launch_bounds__(256) void transpose_cvt(
    const float* __restrict__ W, unsigned short* __restrict__ WT) {
  __shared__ float tile[32][33];
  const int tx = threadIdx.x & 31, ty = threadIdx.x >> 5;
  const int bx = blockIdx.x * 32, by = blockIdx.y * 32;
#pragma unroll
  for (int yy = ty; yy < 32; yy += 8)
    tile[yy][tx] = W[(size_t)(by + yy) * 512 + bx + tx];
  __syncthreads();
#pragma unroll
  for (int yy = ty; yy < 32; yy += 8)
    WT[(size_t)(bx + yy) * 512 + by + tx] = f2bf(tile[tx][yy]);
}

// hin = bf16(x + aggr)   (GIN eps = 0)
__global__ __launch_bounds__(256) void make_hin(
    const float* __restrict__ x, const float* __restrict__ aggr,
    unsigned short* __restrict__ hin, int n4) {
  const int i = blockIdx.x * 256 + threadIdx.x;
  if (i < n4) {
    float4 a = ((const float4*)x)[i];
    float4 b = ((const float4*)aggr)[i];
    ushort4 o;
    o.x = f2bf(a.x + b.x); o.y = f2bf(a.y + b.y);
    o.z = f2bf(a.z + b.z); o.w = f2bf(a.w + b.w);
    ((ushort4*)hin)[i] = o;
  }
}

__global__ __launch_bounds__(256) void bn_stats(
    const float* __restrict__ h2, float* __restrict__ sums,
    float* __restrict__ sumsq, int N) {
  const int c = threadIdx.x;
  const int rpb = (N + gridDim.x - 1) / gridDim.x;
  const int r0 = blockIdx.x * rpb;
  const int r1 = (r0 + rpb) < N ? (r0 + rpb) : N;
  float s0 = 0.f, q0 = 0.f, s1 = 0.f, q1 = 0.f;
  for (int r = r0; r < r1; ++r) {
    float a = h2[(size_t)r * 512 + c];
    float b = h2[(size_t)r * 512 + c + 256];
    s0 += a; q0 += a * a; s1 += b; q1 += b * b;
  }
  atomicAdd(&sums[c], s0);        atomicAdd(&sumsq[c], q0);
  atomicAdd(&sums[c + 256], s1);  atomicAdd(&sumsq[c + 256], q1);
}

__global__ __launch_bounds__(256) void bn_norm(
    const float* __restrict__ h2, const float* __restrict__ sums,
    const float* __restrict__ sumsq, const float* __restrict__ gamma,
    const float* __restrict__ beta, float* __restrict__ out, int n4, float invN) {
  const int i = blockIdx.x * 256 + threadIdx.x;
  if (i >= n4) return;
  const int c4 = (i & 127) * 4;
  float4 h = ((const float4*)h2)[i];
  float hv[4] = {h.x, h.y, h.z, h.w};
  float res[4];
#pragma unroll
  for (int k = 0; k < 4; ++k) {
    const int c = c4 + k;
    float m   = sums[c] * invN;
    float var = sumsq[c] * invN - m * m;
    float sc  = gamma[c] * rsqrtf(var + 1e-5f);
    res[k] = (hv[k] - m) * sc + beta[c];
  }
  float4 o = {res[0], res[1], res[2], res[3]};
  ((float4*)out)[i] = o;
}

// ---------------------------------------------------------------------------
extern "C" void kernel_launch(void* const* d_in, const int* in_sizes, int n_in,
                              void* d_out, int out_size, void* d_ws, size_t ws_size,
                              hipStream_t stream) {
  const float* x     = (const float*)d_in[0];
  const int*   ei    = (const int*)d_in[1];
  const float* ea    = (const float*)d_in[2];
  const float* W_e   = (const float*)d_in[3];
  const float* b_e   = (const float*)d_in[4];
  const float* W1    = (const float*)d_in[5];
  const float* b1    = (const float*)d_in[6];
  const float* W2    = (const float*)d_in[7];
  const float* b2    = (const float*)d_in[8];
  const float* gamma = (const float*)d_in[9];
  const float* beta  = (const float*)d_in[10];
  float* out = (float*)d_out;

  const int N = in_sizes[0] / 512;   // 25000
  const int E = in_sizes[1] / 2;     // 400000
  const int* srcI = ei;
  const int* dstI = ei + E;

  // workspace layout (bytes). ea_bf16 region is dead after edge_gemm and is
  // reused for h2/hin/h1 (lifetimes are disjoint, stream-ordered).
  char* ws = (char*)d_ws;
  unsigned short* eaB = (unsigned short*)(ws + 0);          // 409,600,000
  float*          h2  = (float*)(ws + 0);                   //  51,200,000
  unsigned short* hin = (unsigned short*)(ws + 104857600);  //  25,600,000
  unsigned short* h1  = (unsigned short*)(ws + 157286400);  //  25,600,000
  float*          aggr= (float*)(ws + 409600000);           //  51,200,000
  unsigned short* WeT = (unsigned short*)(ws + 460800000);  //     524,288
  unsigned short* W1T = (unsigned short*)(ws + 461324288);
  unsigned short* W2T = (unsigned short*)(ws + 461848576);
  float*          sums  = (float*)(ws + 462372864);         // 2048
  float*          sumsq = (float*)(ws + 462374912);         // 2048

  hipMemsetAsync(aggr, 0, (size_t)N * 512 * 4, stream);
  hipMemsetAsync(sums, 0, 4096, stream);

  const int en4 = E * 512 / 4;   // 51.2M
  cvt_f32_bf16<<<(en4 + 255) / 256, 256, 0, stream>>>(ea, eaB, en4);
  dim3 tg(16, 16);
  transpose_cvt<<<tg, 256, 0, stream>>>(W_e, WeT);
  transpose_cvt<<<tg, 256, 0, stream>>>(W1, W1T);
  transpose_cvt<<<tg, 256, 0, stream>>>(W2, W2T);

  const int emt = (E + 127) / 128;   // 3125
  edge_gemm<<<emt * 4, 256, 0, stream>>>(eaB, WeT, b_e, x, srcI, dstI, aggr, E);

  const int nn4 = N * 512 / 4;       // 3.2M
  make_hin<<<(nn4 + 255) / 256, 256, 0, stream>>>(x, aggr, hin, nn4);

  const int nmt = (N + 127) / 128;   // 196
  node_gemm_relu<<<nmt * 4, 256, 0, stream>>>(hin, W1T, b1, h1, N);
  node_gemm_f32<<<nmt * 4, 256, 0, stream>>>(h1, W2T, b2, h2, N);

  bn_stats<<<200, 256, 0, stream>>>(h2, sums, sumsq, N);
  bn_norm<<<(nn4 + 255) / 256, 256, 0, stream>>>(h2, sums, sumsq, gamma, beta,
                                                 out, nn4, 1.0f / (float)N);
}